// Round 16
// baseline (53.476 us; speedup 1.0000x reference)
//
#include <hip/hip_runtime.h>
#include <hip/hip_bf16.h>

#define B_ 8
#define C_ 256
#define N_ 1024
#define NH 8

#define SL 0.25507675857f   // log2(e) / sqrt(32)

using bf16x8 = __attribute__((ext_vector_type(8))) short;
using s16x4  = __attribute__((ext_vector_type(4))) short;
using f32x4  = __attribute__((ext_vector_type(4))) float;

__device__ inline short f2bf(float f) {
  union { float f; unsigned u; } v; v.f = f;
  unsigned r = v.u + 0x7fffu + ((v.u >> 16) & 1u);   // RNE
  return (short)(r >> 16);
}

__device__ inline int cvt_pk_bf16(float lo, float hi) {
  int r;
  asm("v_cvt_pk_bf16_f32 %0, %1, %2" : "=v"(r) : "v"(lo), "v"(hi));
  return r;
}

// ---- fused: weight cvt (blocks 0..1023) + GroupNorm (blocks 1024..1279) ----
__global__ __launch_bounds__(256) void pre_kernel(const float* __restrict__ wq,
    const float* __restrict__ wp, short* __restrict__ wbf,
    const float* __restrict__ x, const float* __restrict__ gw,
    const float* __restrict__ gb, short* __restrict__ h_t)
{
  __shared__ float smem[8];
  const int bid = blockIdx.x;
  if (bid < 1024) {
    const int i = bid * 256 + threadIdx.x;
    if (i < 65536)       wbf[i] = f2bf(wq[i] * SL);   // Q weights pre-scaled
    else if (i < 196608) wbf[i] = f2bf(wq[i]);
    else                 wbf[i] = f2bf(wp[i - 196608]);
    return;
  }
  const int bb = (bid - 1024) & 7;
  const int g  = (bid - 1024) >> 3;
  const size_t base = ((size_t)bb * C_ + g * 8) * N_;
  const float* xp = x + base;

  float vals[32];
  float sum = 0.f, sq = 0.f;
#pragma unroll
  for (int r = 0; r < 32; ++r) {
    float v = xp[r * 256 + threadIdx.x];
    vals[r] = v; sum += v; sq += v * v;
  }
#pragma unroll
  for (int off = 32; off; off >>= 1) {
    sum += __shfl_down(sum, off);
    sq  += __shfl_down(sq,  off);
  }
  const int wid = threadIdx.x >> 6;
  if ((threadIdx.x & 63) == 0) { smem[wid] = sum; smem[4 + wid] = sq; }
  __syncthreads();
  sum = smem[0] + smem[1] + smem[2] + smem[3];
  sq  = smem[4] + smem[5] + smem[6] + smem[7];

  const float mu  = sum * (1.f / 8192.f);
  const float var = sq  * (1.f / 8192.f) - mu * mu;
  const float rs  = rsqrtf(var + 1e-5f);

#pragma unroll
  for (int qn = 0; qn < 4; ++qn) {
    short tmp[8];
#pragma unroll
    for (int ch = 0; ch < 8; ++ch) {
      const int cc = g * 8 + ch;
      tmp[ch] = f2bf((vals[ch * 4 + qn] - mu) * rs * gw[cc] + gb[cc]);
    }
    *(bf16x8*)&h_t[((size_t)bb * N_ + qn * 256 + threadIdx.x) * C_ + g * 8] = *(bf16x8*)tmp;
  }
}

// ------- MFMA GEMM body, 64xBN tile, 2-phase reg-staged -------
// MODE 0 (BN=128): A=h_t[b] (rows n), B=W_qk, C=bf16 qk_t, bias[col]
// MODE 1 (BN=64):  A=W_v (rows o), B=h_t[b] (cols n), C=bf16 v_sep, bias[row]
// MODE 2 (BN=64):  A=W_proj, B=att_t[b], C=f32 out + resid, bias[row]
template<int MODE, int BN>
__device__ __forceinline__ void gemm_body(int b, int by, int bz,
    const short* __restrict__ Aw, const short* __restrict__ Bw,
    const float* __restrict__ bias, const float* __restrict__ resid,
    void* __restrict__ Cout)
{
  constexpr int NI = BN / 32;
  const short* A  = (MODE == 0) ? Aw + (size_t)b * N_ * C_ : Aw;
  const short* Bp = (MODE == 0) ? Bw : Bw + (size_t)b * N_ * C_;

  const int tid = threadIdx.x;
  const int lane = tid & 63, wid = tid >> 6;
  const int g = lane >> 4, c = lane & 15;
  const int wm = wid >> 1, wn = wid & 1;
  const int m0 = by * 64, n0 = bz * BN;

  __shared__ short At[64][72];
  __shared__ short Bt[BN][72];

  const int srow = tid >> 3, sseg = tid & 7;
  bf16x8 areg[2], breg[NI];
#pragma unroll
  for (int j = 0; j < 2; ++j)
    areg[j] = *(const bf16x8*)&A[(size_t)(m0 + srow + j * 32) * 256 + sseg * 8];
#pragma unroll
  for (int j = 0; j < NI; ++j)
    breg[j] = *(const bf16x8*)&Bp[(size_t)(n0 + srow + j * 32) * 256 + sseg * 8];

  f32x4 acc[2][NI] = {};

  for (int kb = 0; kb < 256; kb += 64) {
    __syncthreads();
#pragma unroll
    for (int j = 0; j < 2; ++j) *(bf16x8*)&At[srow + j * 32][sseg * 8] = areg[j];
#pragma unroll
    for (int j = 0; j < NI; ++j) *(bf16x8*)&Bt[srow + j * 32][sseg * 8] = breg[j];
    __syncthreads();

    if (kb < 192) {
      const int kn = kb + 64;
#pragma unroll
      for (int j = 0; j < 2; ++j)
        areg[j] = *(const bf16x8*)&A[(size_t)(m0 + srow + j * 32) * 256 + kn + sseg * 8];
#pragma unroll
      for (int j = 0; j < NI; ++j)
        breg[j] = *(const bf16x8*)&Bp[(size_t)(n0 + srow + j * 32) * 256 + kn + sseg * 8];
    }

#pragma unroll
    for (int kk = 0; kk < 2; ++kk) {
      bf16x8 af[2], bfr[NI];
#pragma unroll
      for (int mi = 0; mi < 2; ++mi)
        af[mi] = *(const bf16x8*)&At[wm * 32 + mi * 16 + c][kk * 32 + g * 8];
#pragma unroll
      for (int ni = 0; ni < NI; ++ni)
        bfr[ni] = *(const bf16x8*)&Bt[wn * (BN / 2) + ni * 16 + c][kk * 32 + g * 8];
#pragma unroll
      for (int mi = 0; mi < 2; ++mi)
#pragma unroll
        for (int ni = 0; ni < NI; ++ni)
          acc[mi][ni] = __builtin_amdgcn_mfma_f32_16x16x32_bf16(af[mi], bfr[ni],
                                                                acc[mi][ni], 0, 0, 0);
    }
  }

#pragma unroll
  for (int mi = 0; mi < 2; ++mi)
#pragma unroll
    for (int ni = 0; ni < NI; ++ni) {
      const int col = n0 + wn * (BN / 2) + ni * 16 + c;
#pragma unroll
      for (int r = 0; r < 4; ++r) {
        const int row = m0 + wm * 32 + mi * 16 + g * 4 + r;
        float v = acc[mi][ni][r];
        if (MODE == 0) {
          v += (col < 256) ? bias[col] * SL : bias[col];
          ((short*)Cout)[((size_t)b * N_ + row) * 512 + col] = f2bf(v);
        } else if (MODE == 1) {
          v += bias[row];
          ((short*)Cout)[((size_t)b * 256 + row) * N_ + col] = f2bf(v);
        } else {
          v += bias[row] + resid[((size_t)b * 256 + row) * N_ + col];
          ((float*)Cout)[((size_t)b * 256 + row) * N_ + col] = v;
        }
      }
    }
}

// fused QKV: blocks 0..511 = Q|K gemm (MODE0, BN128), 512..1023 = V gemm (MODE1, BN64)
__global__ __launch_bounds__(256) void qkv_kernel(const short* __restrict__ h_t,
    const short* __restrict__ wbf, const float* __restrict__ qkv_b,
    short* __restrict__ qk_t, short* __restrict__ v_sep)
{
  const int bid = blockIdx.x;
  if (bid < 512)
    gemm_body<0, 128>(bid & 7, (bid >> 3) & 15, bid >> 7, h_t, wbf, qkv_b, nullptr, qk_t);
  else {
    const int b2 = bid - 512;
    gemm_body<1, 64>(b2 & 7, (b2 >> 3) & 3, b2 >> 5, wbf + 512 * 256, h_t,
                     qkv_b + 512, nullptr, v_sep);
  }
}

__global__ __launch_bounds__(256) void proj_kernel(const short* __restrict__ wbf,
    const short* __restrict__ att_t, const float* __restrict__ pj_b,
    const float* __restrict__ x, float* __restrict__ out)
{
  const int bid = blockIdx.x;
  gemm_body<2, 64>(bid & 7, (bid >> 3) & 3, bid >> 5, wbf + 768 * 256, att_t, pj_b, x, out);
}

// ---------------- LDS-free MFMA flash attention, q128 x 4-way split-KV, two-pass ----------------
// grid (B*NH, 8), 4 waves = 4 KV quarters; each wave covers ALL 128 q-rows as
// TWO back-to-back 4-m passes of r13's batched-phase inner loop over its
// 4-tile quarter -> per-block K/V tile-loads 16 (r13: 32) at IDENTICAL
// pipeline shape (same pass count, same per-phase ILP, same prefetch slots:
// kf refilled after pass-2 QK, vv after pass-2 PV). Fixed-shift softmax
// partials exactly summable: waves 1-3 dump acc+lsum to xls[3][64][73]
// (stride-73: gcd(9,32)=1, conflict-free), one barrier, wave 0 merges.
__global__ __launch_bounds__(256) void attn_mfma(const short* __restrict__ qkt,
    const short* __restrict__ v_sep, short* __restrict__ att_t)
{
  const int bh = blockIdx.x;
  const int b = bh >> 3, hh = bh & 7;
  const int q0 = blockIdx.y * 128;

  const int tid  = threadIdx.x;
  const int w    = tid >> 6;          // KV quarter
  const int lane = tid & 63;
  const int g = lane >> 4, c = lane & 15;

  const short* qk_b = qkt + (size_t)b * N_ * 512;
  const short* v_b  = v_sep + ((size_t)b * 256 + hh * 32) * N_;

  bf16x8 qb[8];
#pragma unroll
  for (int m = 0; m < 8; ++m)
    qb[m] = *(const bf16x8*)&qk_b[(size_t)(q0 + m * 16 + c) * 512 + hh * 32 + g * 8];

  // permuted K row pointers: krow(kc,c) = (kc&1)*32 + (c>>2)*8 + (kc>>1)*4 + (c&3)
  const short* kp[4];
#pragma unroll
  for (int kc = 0; kc < 4; ++kc) {
    const int krow = (kc & 1) * 32 + (c >> 2) * 8 + ((kc >> 1) << 2) + (c & 3);
    kp[kc] = qk_b + (size_t)krow * 512 + 256 + hh * 32 + g * 8;
  }
  const short* vpA = v_b + (size_t)c * N_ + g * 8;          // V rows c      (dd=0)
  const short* vpB = v_b + (size_t)(16 + c) * N_ + g * 8;   // V rows 16+c   (dd=1)

  f32x4 acc[8][2] = {};
  float lsum[8] = {0.f, 0.f, 0.f, 0.f, 0.f, 0.f, 0.f, 0.f};
  const f32x4 cinit = {-16.f, -16.f, -16.f, -16.f};

  const int t0 = w * 4;               // this wave's 4-tile KV quarter
  bf16x8 kf[4], vv[4];
#pragma unroll
  for (int kc = 0; kc < 4; ++kc)
    kf[kc] = *(const bf16x8*)(kp[kc] + (size_t)t0 * 64 * 512);
  vv[0] = *(const bf16x8*)(vpA + t0 * 64);
  vv[1] = *(const bf16x8*)(vpA + t0 * 64 + 32);
  vv[2] = *(const bf16x8*)(vpB + t0 * 64);
  vv[3] = *(const bf16x8*)(vpB + t0 * 64 + 32);

  for (int ii = 0; ii < 4; ++ii) {
    const int kt = t0 + ii;
#pragma unroll
    for (int pass = 0; pass < 2; ++pass) {
      int pk[4][4][2];
#pragma unroll
      for (int mm = 0; mm < 4; ++mm) {
        const int m = pass * 4 + mm;
        f32x4 s[4];
        __builtin_amdgcn_s_setprio(1);
#pragma unroll
        for (int kc = 0; kc < 4; ++kc)
          s[kc] = __builtin_amdgcn_mfma_f32_16x16x32_bf16(kf[kc], qb[m], cinit, 0, 0, 0);
        __builtin_amdgcn_s_setprio(0);
        float sum = 0.f;
#pragma unroll
        for (int kc = 0; kc < 4; ++kc) {
#pragma unroll
          for (int r = 0; r < 4; ++r) {
            s[kc][r] = __builtin_amdgcn_exp2f(s[kc][r]);
            sum += s[kc][r];
          }
          pk[mm][kc][0] = cvt_pk_bf16(s[kc][0], s[kc][1]);
          pk[mm][kc][1] = cvt_pk_bf16(s[kc][2], s[kc][3]);
        }
        lsum[m] += sum;
      }

      if (pass == 1 && ii < 3) {      // kf dead after pass-2 QK: prefetch next tile
#pragma unroll
        for (int kc = 0; kc < 4; ++kc)
          kf[kc] = *(const bf16x8*)(kp[kc] + (size_t)(kt + 1) * 64 * 512);
      }

      __builtin_amdgcn_s_setprio(1);
#pragma unroll
      for (int mm = 0; mm < 4; ++mm)
#pragma unroll
        for (int ks = 0; ks < 2; ++ks) {
          union { bf16x8 v; int i[4]; } pb;
          pb.i[0] = pk[mm][ks][0];
          pb.i[1] = pk[mm][ks][1];
          pb.i[2] = pk[mm][ks + 2][0];
          pb.i[3] = pk[mm][ks + 2][1];
          acc[pass * 4 + mm][0] = __builtin_amdgcn_mfma_f32_16x16x32_bf16(
              ks ? vv[1] : vv[0], pb.v, acc[pass * 4 + mm][0], 0, 0, 0);
          acc[pass * 4 + mm][1] = __builtin_amdgcn_mfma_f32_16x16x32_bf16(
              ks ? vv[3] : vv[2], pb.v, acc[pass * 4 + mm][1], 0, 0, 0);
        }
      __builtin_amdgcn_s_setprio(0);

      if (pass == 1 && ii < 3) {      // vv dead after pass-2 PV: prefetch next tile
        vv[0] = *(const bf16x8*)(vpA + (kt + 1) * 64);
        vv[1] = *(const bf16x8*)(vpA + (kt + 1) * 64 + 32);
        vv[2] = *(const bf16x8*)(vpB + (kt + 1) * 64);
        vv[3] = *(const bf16x8*)(vpB + (kt + 1) * 64 + 32);
      }
    }
  }

  // per-wave lane-group reduce of denominators
#pragma unroll
  for (int m = 0; m < 8; ++m) {
    lsum[m] += __shfl_xor(lsum[m], 16);
    lsum[m] += __shfl_xor(lsum[m], 32);
  }

  // cross-wave merge: waves 1-3 dump, wave 0 sums (exact fixed-shift partials)
  __shared__ float xls[3][64][73];     // stride 73: lane->bank gcd(9,32)=1, conflict-free
  if (w != 0) {
    float* row = &xls[w - 1][lane][0];
#pragma unroll
    for (int m = 0; m < 8; ++m) {
#pragma unroll
      for (int dd = 0; dd < 2; ++dd)
#pragma unroll
        for (int r = 0; r < 4; ++r)
          row[m * 9 + dd * 4 + r] = acc[m][dd][r];
      row[m * 9 + 8] = lsum[m];
    }
  }
  __syncthreads();
  if (w == 0) {
#pragma unroll
    for (int m = 0; m < 8; ++m) {
      float a[8];
#pragma unroll
      for (int dd = 0; dd < 2; ++dd)
#pragma unroll
        for (int r = 0; r < 4; ++r) a[dd * 4 + r] = acc[m][dd][r];
      float l = lsum[m];
#pragma unroll
      for (int p = 0; p < 3; ++p) {
        const float* row = &xls[p][lane][0];
#pragma unroll
        for (int j = 0; j < 8; ++j) a[j] += row[m * 9 + j];
        l += row[m * 9 + 8];
      }
      const float inv = 1.f / l;
      const int q = q0 + m * 16 + c;
#pragma unroll
      for (int dd = 0; dd < 2; ++dd) {
        short st[4];
#pragma unroll
        for (int r = 0; r < 4; ++r) st[r] = f2bf(a[dd * 4 + r] * inv);
        *(s16x4*)&att_t[((size_t)b * N_ + q) * C_ + hh * 32 + dd * 16 + g * 4] = *(s16x4*)st;
      }
    }
  }
}

extern "C" void kernel_launch(void* const* d_in, const int* in_sizes, int n_in,
                              void* d_out, int out_size, void* d_ws, size_t ws_size,
                              hipStream_t stream)
{
  const float* x     = (const float*)d_in[0];
  const float* gn_w  = (const float*)d_in[1];
  const float* gn_b  = (const float*)d_in[2];
  const float* qkv_w = (const float*)d_in[3];
  const float* qkv_b = (const float*)d_in[4];
  const float* pj_w  = (const float*)d_in[5];
  const float* pj_b  = (const float*)d_in[6];
  float* out = (float*)d_out;

  short* h_t   = (short*)d_ws;                    // 8*1024*256
  short* qk_t  = h_t   + (size_t)B_ * N_ * C_;    // 8*1024*512  (Q|K, n-major)
  short* v_sep = qk_t  + (size_t)B_ * N_ * 512;   // 8*256*1024  (V, d-major)
  short* att_t = v_sep + (size_t)B_ * C_ * N_;    // 8*1024*256
  short* wbf   = att_t + (size_t)B_ * N_ * C_;    // 262144

  pre_kernel <<<1280, 256, 0, stream>>>(qkv_w, pj_w, wbf, x, gn_w, gn_b, h_t);
  qkv_kernel <<<1024, 256, 0, stream>>>(h_t, wbf, qkv_b, qk_t, v_sep);
  attn_mfma  <<<dim3(B_ * NH, 8), 256, 0, stream>>>(qk_t, v_sep, att_t);
  proj_kernel<<<512,  256, 0, stream>>>(wbf, att_t, pj_b, x, out);
}

// Round 17
// 47.122 us; speedup vs baseline: 1.1349x; 1.1349x over previous
//
#include <hip/hip_runtime.h>
#include <hip/hip_bf16.h>

#define B_ 8
#define C_ 256
#define N_ 1024
#define NH 8

#define SL 0.25507675857f   // log2(e) / sqrt(32)

using bf16x8 = __attribute__((ext_vector_type(8))) short;
using s16x4  = __attribute__((ext_vector_type(4))) short;
using f32x4  = __attribute__((ext_vector_type(4))) float;

__device__ inline short f2bf(float f) {
  union { float f; unsigned u; } v; v.f = f;
  unsigned r = v.u + 0x7fffu + ((v.u >> 16) & 1u);   // RNE
  return (short)(r >> 16);
}

__device__ inline int cvt_pk_bf16(float lo, float hi) {
  int r;
  asm("v_cvt_pk_bf16_f32 %0, %1, %2" : "=v"(r) : "v"(lo), "v"(hi));
  return r;
}

// ---- fused: weight cvt float4 (blocks 0..255) + GroupNorm (blocks 256..511) ----
__global__ __launch_bounds__(256) void pre_kernel(const float* __restrict__ wq,
    const float* __restrict__ wp, short* __restrict__ wbf,
    const float* __restrict__ x, const float* __restrict__ gw,
    const float* __restrict__ gb, short* __restrict__ h_t)
{
  __shared__ float smem[8];
  const int bid = blockIdx.x;
  if (bid < 256) {
    const int i = (bid * 256 + threadIdx.x) * 4;   // 262144 total, 4/thread
    float4 v;
    if (i < 196608) v = *(const float4*)&wq[i];
    else            v = *(const float4*)&wp[i - 196608];
    const float sc = (i < 65536) ? SL : 1.f;       // Q weights pre-scaled
    short t[4] = { f2bf(v.x * sc), f2bf(v.y * sc), f2bf(v.z * sc), f2bf(v.w * sc) };
    *(s16x4*)&wbf[i] = *(s16x4*)t;
    return;
  }
  const int bb = (bid - 256) & 7;
  const int g  = (bid - 256) >> 3;
  const size_t base = ((size_t)bb * C_ + g * 8) * N_;
  const float* xp = x + base;

  float vals[32];
  float sum = 0.f, sq = 0.f;
#pragma unroll
  for (int r = 0; r < 32; ++r) {
    float v = xp[r * 256 + threadIdx.x];
    vals[r] = v; sum += v; sq += v * v;
  }
#pragma unroll
  for (int off = 32; off; off >>= 1) {
    sum += __shfl_down(sum, off);
    sq  += __shfl_down(sq,  off);
  }
  const int wid = threadIdx.x >> 6;
  if ((threadIdx.x & 63) == 0) { smem[wid] = sum; smem[4 + wid] = sq; }
  __syncthreads();
  sum = smem[0] + smem[1] + smem[2] + smem[3];
  sq  = smem[4] + smem[5] + smem[6] + smem[7];

  const float mu  = sum * (1.f / 8192.f);
  const float var = sq  * (1.f / 8192.f) - mu * mu;
  const float rs  = rsqrtf(var + 1e-5f);

#pragma unroll
  for (int qn = 0; qn < 4; ++qn) {
    short tmp[8];
#pragma unroll
    for (int ch = 0; ch < 8; ++ch) {
      const int cc = g * 8 + ch;
      tmp[ch] = f2bf((vals[ch * 4 + qn] - mu) * rs * gw[cc] + gb[cc]);
    }
    *(bf16x8*)&h_t[((size_t)bb * N_ + qn * 256 + threadIdx.x) * C_ + g * 8] = *(bf16x8*)tmp;
  }
}

// ------- MFMA GEMM body, 64xBN tile, 2-phase reg-staged -------
// MODE 0 (BN=128): A=h_t[b] (rows n), B=W_qk, C=bf16 qk_t, bias[col]
// MODE 1 (BN=64):  A=W_v (rows o), B=h_t[b] (cols n), C=bf16 v_sep, bias[row]
// MODE 2 (BN=64):  A=W_proj, B=att_t[b], C=f32 out + resid, bias[row]
template<int MODE, int BN>
__device__ __forceinline__ void gemm_body(int b, int by, int bz,
    const short* __restrict__ Aw, const short* __restrict__ Bw,
    const float* __restrict__ bias, const float* __restrict__ resid,
    void* __restrict__ Cout)
{
  constexpr int NI = BN / 32;
  const short* A  = (MODE == 0) ? Aw + (size_t)b * N_ * C_ : Aw;
  const short* Bp = (MODE == 0) ? Bw : Bw + (size_t)b * N_ * C_;

  const int tid = threadIdx.x;
  const int lane = tid & 63, wid = tid >> 6;
  const int g = lane >> 4, c = lane & 15;
  const int wm = wid >> 1, wn = wid & 1;
  const int m0 = by * 64, n0 = bz * BN;

  __shared__ short At[64][72];
  __shared__ short Bt[BN][72];

  const int srow = tid >> 3, sseg = tid & 7;
  bf16x8 areg[2], breg[NI];
#pragma unroll
  for (int j = 0; j < 2; ++j)
    areg[j] = *(const bf16x8*)&A[(size_t)(m0 + srow + j * 32) * 256 + sseg * 8];
#pragma unroll
  for (int j = 0; j < NI; ++j)
    breg[j] = *(const bf16x8*)&Bp[(size_t)(n0 + srow + j * 32) * 256 + sseg * 8];

  f32x4 acc[2][NI] = {};

  for (int kb = 0; kb < 256; kb += 64) {
    __syncthreads();
#pragma unroll
    for (int j = 0; j < 2; ++j) *(bf16x8*)&At[srow + j * 32][sseg * 8] = areg[j];
#pragma unroll
    for (int j = 0; j < NI; ++j) *(bf16x8*)&Bt[srow + j * 32][sseg * 8] = breg[j];
    __syncthreads();

    if (kb < 192) {
      const int kn = kb + 64;
#pragma unroll
      for (int j = 0; j < 2; ++j)
        areg[j] = *(const bf16x8*)&A[(size_t)(m0 + srow + j * 32) * 256 + kn + sseg * 8];
#pragma unroll
      for (int j = 0; j < NI; ++j)
        breg[j] = *(const bf16x8*)&Bp[(size_t)(n0 + srow + j * 32) * 256 + kn + sseg * 8];
    }

#pragma unroll
    for (int kk = 0; kk < 2; ++kk) {
      bf16x8 af[2], bfr[NI];
#pragma unroll
      for (int mi = 0; mi < 2; ++mi)
        af[mi] = *(const bf16x8*)&At[wm * 32 + mi * 16 + c][kk * 32 + g * 8];
#pragma unroll
      for (int ni = 0; ni < NI; ++ni)
        bfr[ni] = *(const bf16x8*)&Bt[wn * (BN / 2) + ni * 16 + c][kk * 32 + g * 8];
#pragma unroll
      for (int mi = 0; mi < 2; ++mi)
#pragma unroll
        for (int ni = 0; ni < NI; ++ni)
          acc[mi][ni] = __builtin_amdgcn_mfma_f32_16x16x32_bf16(af[mi], bfr[ni],
                                                                acc[mi][ni], 0, 0, 0);
    }
  }

#pragma unroll
  for (int mi = 0; mi < 2; ++mi)
#pragma unroll
    for (int ni = 0; ni < NI; ++ni) {
      const int col = n0 + wn * (BN / 2) + ni * 16 + c;
#pragma unroll
      for (int r = 0; r < 4; ++r) {
        const int row = m0 + wm * 32 + mi * 16 + g * 4 + r;
        float v = acc[mi][ni][r];
        if (MODE == 0) {
          v += (col < 256) ? bias[col] * SL : bias[col];
          ((short*)Cout)[((size_t)b * N_ + row) * 512 + col] = f2bf(v);
        } else if (MODE == 1) {
          v += bias[row];
          ((short*)Cout)[((size_t)b * 256 + row) * N_ + col] = f2bf(v);
        } else {
          v += bias[row] + resid[((size_t)b * 256 + row) * N_ + col];
          ((float*)Cout)[((size_t)b * 256 + row) * N_ + col] = v;
        }
      }
    }
}

// fused QKV: blocks 0..511 = Q|K gemm (MODE0, BN128), 512..1023 = V gemm (MODE1, BN64)
__global__ __launch_bounds__(256) void qkv_kernel(const short* __restrict__ h_t,
    const short* __restrict__ wbf, const float* __restrict__ qkv_b,
    short* __restrict__ qk_t, short* __restrict__ v_sep)
{
  const int bid = blockIdx.x;
  if (bid < 512)
    gemm_body<0, 128>(bid & 7, (bid >> 3) & 15, bid >> 7, h_t, wbf, qkv_b, nullptr, qk_t);
  else {
    const int b2 = bid - 512;
    gemm_body<1, 64>(b2 & 7, (b2 >> 3) & 3, b2 >> 5, wbf + 512 * 256, h_t,
                     qkv_b + 512, nullptr, v_sep);
  }
}

__global__ __launch_bounds__(256) void proj_kernel(const short* __restrict__ wbf,
    const short* __restrict__ att_t, const float* __restrict__ pj_b,
    const float* __restrict__ x, float* __restrict__ out)
{
  const int bid = blockIdx.x;
  gemm_body<2, 64>(bid & 7, (bid >> 3) & 3, bid >> 5, wbf + 768 * 256, att_t, pj_b, x, out);
}

// ---------------- LDS-free MFMA flash attention, split-KV across waves (r13) ----------------
// grid (B*NH, 8), 4 waves = (q-half x kv-half). Each wave: 64 q-rows (m=0..3)
// over 8 KV tiles. Fixed-shift softmax (p = exp2(s*SL-16), no max tracking)
// makes partials exactly summable: kv-half-1 waves dump acc+lsum to LDS
// (single barrier), kv-half-0 waves add, normalize, store.
// K rows permuted at load (krow(kc,c)) -> zero-shuffle P handoff.
__global__ __launch_bounds__(256) void attn_mfma(const short* __restrict__ qkt,
    const short* __restrict__ v_sep, short* __restrict__ att_t)
{
  const int bh = blockIdx.x;
  const int b = bh >> 3, hh = bh & 7;
  const int tid  = threadIdx.x;
  const int w    = tid >> 6;
  const int qhalf = w >> 1, kvh = w & 1;
  const int lane = tid & 63;
  const int g = lane >> 4, c = lane & 15;
  const int q0 = blockIdx.y * 128 + qhalf * 64;

  const short* qk_b = qkt + (size_t)b * N_ * 512;
  const short* v_b  = v_sep + ((size_t)b * 256 + hh * 32) * N_;

  bf16x8 qb[4];
#pragma unroll
  for (int m = 0; m < 4; ++m)
    qb[m] = *(const bf16x8*)&qk_b[(size_t)(q0 + m * 16 + c) * 512 + hh * 32 + g * 8];

  // permuted K row pointers: krow(kc,c) = (kc&1)*32 + (c>>2)*8 + (kc>>1)*4 + (c&3)
  const short* kp[4];
#pragma unroll
  for (int kc = 0; kc < 4; ++kc) {
    const int krow = (kc & 1) * 32 + (c >> 2) * 8 + ((kc >> 1) << 2) + (c & 3);
    kp[kc] = qk_b + (size_t)krow * 512 + 256 + hh * 32 + g * 8;
  }
  const short* vpA = v_b + (size_t)c * N_ + g * 8;          // V rows c      (dd=0)
  const short* vpB = v_b + (size_t)(16 + c) * N_ + g * 8;   // V rows 16+c   (dd=1)

  f32x4 acc[4][2] = {};
  float lsum[4] = {0.f, 0.f, 0.f, 0.f};
  const f32x4 cinit = {-16.f, -16.f, -16.f, -16.f};

  const int t0 = kvh * 8;                  // this wave's 8-tile KV half
  bf16x8 kf[4], vv[4];
#pragma unroll
  for (int kc = 0; kc < 4; ++kc)
    kf[kc] = *(const bf16x8*)(kp[kc] + (size_t)t0 * 64 * 512);
  vv[0] = *(const bf16x8*)(vpA + t0 * 64);
  vv[1] = *(const bf16x8*)(vpA + t0 * 64 + 32);
  vv[2] = *(const bf16x8*)(vpB + t0 * 64);
  vv[3] = *(const bf16x8*)(vpB + t0 * 64 + 32);

  for (int ii = 0; ii < 8; ++ii) {
    const int kt = t0 + ii;
    int pk[4][4][2];
#pragma unroll
    for (int m = 0; m < 4; ++m) {
      f32x4 s[4];
      __builtin_amdgcn_s_setprio(1);
#pragma unroll
      for (int kc = 0; kc < 4; ++kc)
        s[kc] = __builtin_amdgcn_mfma_f32_16x16x32_bf16(kf[kc], qb[m], cinit, 0, 0, 0);
      __builtin_amdgcn_s_setprio(0);
      float sum = 0.f;
#pragma unroll
      for (int kc = 0; kc < 4; ++kc) {
#pragma unroll
        for (int r = 0; r < 4; ++r) {
          s[kc][r] = __builtin_amdgcn_exp2f(s[kc][r]);
          sum += s[kc][r];
        }
        pk[m][kc][0] = cvt_pk_bf16(s[kc][0], s[kc][1]);
        pk[m][kc][1] = cvt_pk_bf16(s[kc][2], s[kc][3]);
      }
      lsum[m] += sum;
    }

    if (ii < 7) {                          // prefetch next K tile
#pragma unroll
      for (int kc = 0; kc < 4; ++kc)
        kf[kc] = *(const bf16x8*)(kp[kc] + (size_t)(kt + 1) * 64 * 512);
    }

    __builtin_amdgcn_s_setprio(1);
#pragma unroll
    for (int m = 0; m < 4; ++m)
#pragma unroll
      for (int ks = 0; ks < 2; ++ks) {
        union { bf16x8 v; int i[4]; } pb;
        pb.i[0] = pk[m][ks][0];
        pb.i[1] = pk[m][ks][1];
        pb.i[2] = pk[m][ks + 2][0];
        pb.i[3] = pk[m][ks + 2][1];
        acc[m][0] = __builtin_amdgcn_mfma_f32_16x16x32_bf16(ks ? vv[1] : vv[0], pb.v,
                                                            acc[m][0], 0, 0, 0);
        acc[m][1] = __builtin_amdgcn_mfma_f32_16x16x32_bf16(ks ? vv[3] : vv[2], pb.v,
                                                            acc[m][1], 0, 0, 0);
      }
    __builtin_amdgcn_s_setprio(0);

    if (ii < 7) {                          // prefetch next V tile
      vv[0] = *(const bf16x8*)(vpA + (kt + 1) * 64);
      vv[1] = *(const bf16x8*)(vpA + (kt + 1) * 64 + 32);
      vv[2] = *(const bf16x8*)(vpB + (kt + 1) * 64);
      vv[3] = *(const bf16x8*)(vpB + (kt + 1) * 64 + 32);
    }
  }

  // per-wave lane-group reduce of the denominators
#pragma unroll
  for (int m = 0; m < 4; ++m) {
    lsum[m] += __shfl_xor(lsum[m], 16);
    lsum[m] += __shfl_xor(lsum[m], 32);
  }

  // cross-wave merge of the two KV halves (exact: fixed-shift partials sum)
  __shared__ float xls[2][64][37];         // 37-pad: lane stride 148B, spread banks
  if (kvh == 1) {
#pragma unroll
    for (int m = 0; m < 4; ++m) {
#pragma unroll
      for (int dd = 0; dd < 2; ++dd)
#pragma unroll
        for (int r = 0; r < 4; ++r)
          xls[qhalf][lane][m * 8 + dd * 4 + r] = acc[m][dd][r];
      xls[qhalf][lane][32 + m] = lsum[m];
    }
  }
  __syncthreads();
  if (kvh == 0) {
#pragma unroll
    for (int m = 0; m < 4; ++m) {
      const float l = lsum[m] + xls[qhalf][lane][32 + m];
      const float inv = 1.f / l;
      const int q = q0 + m * 16 + c;
#pragma unroll
      for (int dd = 0; dd < 2; ++dd) {
        short st[4];
#pragma unroll
        for (int r = 0; r < 4; ++r)
          st[r] = f2bf((acc[m][dd][r] + xls[qhalf][lane][m * 8 + dd * 4 + r]) * inv);
        *(s16x4*)&att_t[((size_t)b * N_ + q) * C_ + hh * 32 + dd * 16 + g * 4] = *(s16x4*)st;
      }
    }
  }
}

extern "C" void kernel_launch(void* const* d_in, const int* in_sizes, int n_in,
                              void* d_out, int out_size, void* d_ws, size_t ws_size,
                              hipStream_t stream)
{
  const float* x     = (const float*)d_in[0];
  const float* gn_w  = (const float*)d_in[1];
  const float* gn_b  = (const float*)d_in[2];
  const float* qkv_w = (const float*)d_in[3];
  const float* qkv_b = (const float*)d_in[4];
  const float* pj_w  = (const float*)d_in[5];
  const float* pj_b  = (const float*)d_in[6];
  float* out = (float*)d_out;

  short* h_t   = (short*)d_ws;                    // 8*1024*256
  short* qk_t  = h_t   + (size_t)B_ * N_ * C_;    // 8*1024*512  (Q|K, n-major)
  short* v_sep = qk_t  + (size_t)B_ * N_ * 512;   // 8*256*1024  (V, d-major)
  short* att_t = v_sep + (size_t)B_ * C_ * N_;    // 8*1024*256
  short* wbf   = att_t + (size_t)B_ * N_ * C_;    // 262144

  pre_kernel <<<512,  256, 0, stream>>>(qkv_w, pj_w, wbf, x, gn_w, gn_b, h_t);
  qkv_kernel <<<1024, 256, 0, stream>>>(h_t, wbf, qkv_b, qk_t, v_sep);
  attn_mfma  <<<dim3(B_ * NH, 8), 256, 0, stream>>>(qk_t, v_sep, att_t);
  proj_kernel<<<512,  256, 0, stream>>>(wbf, att_t, pj_b, x, out);
}